// Round 10
// baseline (516.762 us; speedup 1.0000x reference)
//
#include <hip/hip_runtime.h>

typedef float v16f __attribute__((ext_vector_type(16)));
typedef int v8i __attribute__((ext_vector_type(8)));
typedef int v4i __attribute__((ext_vector_type(4)));
typedef int v2i __attribute__((ext_vector_type(2)));
typedef unsigned short ushort_t;
typedef unsigned char uchar_t;
typedef long long ll_t;

#define HH 768
#define WW 768
#define CH 3
#define KS 24
#define HC 745
#define WC 745
#define NP 256
#define XH 384
#define XW 384

#define NBX 24            // ceil(745/32)
#define NBY 187           // ceil(745/4)
#define NBLK (NBX*NBY)    // 4488
#define BROWS 4
#define BCOLS 32
#define NSTEP 27          // K=1728 in 64-wide slices (8 octets each)
#define NCAND 8
#define NGRID (8*1152)    // XCD-banded launch (some idle)

__device__ __forceinline__ ushort_t f2bf(float f) {
    union { __bf16 h; ushort_t u; } cv; cv.h = (__bf16)f; return cv.u;
}
__device__ __forceinline__ float bf2f(ushort_t u) {
    union { unsigned u; float f; } cv; cv.u = ((unsigned)u) << 16; return cv.f;
}
// fp32 -> OCP e4m3fn (RNE for normals; grid-round for subnormals). Screen-only precision.
__device__ __forceinline__ uchar_t f2e4m3(float f) {
    unsigned u = __float_as_uint(f);
    unsigned s = (u >> 24) & 0x80;
    float a = fabsf(f);
    if (a < 0.0078125f) {
        int q = (int)(a * 512.0f + 0.5f);
        return (uchar_t)(s | (unsigned)q);
    }
    int e = (int)((u >> 23) & 0xFF);
    unsigned m = (u >> 20) & 7;
    unsigned rest = u & 0xFFFFF;
    if (rest > 0x80000 || (rest == 0x80000 && (m & 1))) { m++; if (m == 8) { m = 0; e++; } }
    int e8 = e - 120;
    if (e8 <= 0) { int q = (int)(a * 512.0f + 0.5f); if (q > 7) q = 7; return (uchar_t)(s | q); }
    if (e8 > 15) return (uchar_t)(s | 0x7E);
    return (uchar_t)(s | ((unsigned)e8 << 3) | m);
}

// -------------------- prep kernels --------------------

__global__ void k_colsum(const float* __restrict__ y, float* __restrict__ ksum,
                         float* __restrict__ ksum2) {
    int idx = blockIdx.x * 256 + threadIdx.x;
    if (idx >= HH * WW) return;
    float a = y[idx], b = y[idx + HH * WW], c = y[idx + 2 * HH * WW];
    ksum[idx]  = a + b + c;
    ksum2[idx] = a * a + b * b + c * c;
}

__global__ void k_hsum(const float* __restrict__ ksum, const float* __restrict__ ksum2,
                       float* __restrict__ h1, float* __restrict__ h2) {
    int idx = blockIdx.x * 256 + threadIdx.x;
    if (idx >= HH * WC) return;
    int h = idx / WC, w = idx % WC;
    const float* r  = ksum  + h * WW + w;
    const float* r2 = ksum2 + h * WW + w;
    float s = 0.f, s2 = 0.f;
    #pragma unroll
    for (int j = 0; j < KS; j++) { s += r[j]; s2 += r2[j]; }
    h1[idx] = s; h2[idx] = s2;
}

// packed bf16 map: sv[pos] = (ivm<<16) | s1m — ONE epilogue load instead of two.
// Screen-only precision; k_rescore recomputes exactly.
__global__ void k_vsum(const float* __restrict__ h1, const float* __restrict__ h2,
                       unsigned* __restrict__ sv) {
    int idx = blockIdx.x * 256 + threadIdx.x;
    if (idx >= HC * WC) return;
    int r = idx / WC, w = idx % WC;
    float s = 0.f, s2 = 0.f;
    #pragma unroll
    for (int i = 0; i < KS; i++) { s += h1[(r + i) * WC + w]; s2 += h2[(r + i) * WC + w]; }
    float d2 = s2 - s * s * (1.0f / 576.0f);
    sv[idx] = ((unsigned)f2bf(rsqrtf(fmaxf(d2, 1e-20f))) << 16) | (unsigned)f2bf(s);
}

__global__ void k_meanx(const float* __restrict__ x, float* __restrict__ mx) {
    int p = blockIdx.x;
    int pr = p >> 4, pc = p & 15;
    float s = 0.f;
    for (int e = threadIdx.x; e < CH * KS * KS; e += 256) {
        int c = e / (KS * KS); int rem = e % (KS * KS);
        int i = rem / KS, j = rem % KS;
        s += x[(c * XH + pr * KS + i) * XW + pc * KS + j];
    }
    __shared__ float red[256];
    red[threadIdx.x] = s; __syncthreads();
    for (int st = 128; st > 0; st >>= 1) {
        if (threadIdx.x < st) red[threadIdx.x] += red[threadIdx.x + st];
        __syncthreads();
    }
    if (threadIdx.x == 0) mx[p] = red[0] * (1.0f / 1728.0f);
}

// fp8 patch matrix, K-REORDERED and lane-contiguous (R3/R4/R6/R7-verified layout):
//   k-plane o' = (j/8)*72 + c*24 + i (0..215), slice s = o'>>3, w = o'&7, h = w>>2, q = w&3.
//   addr = (((s*2+h)*2 + (q>>1))*256 + p)*16 + (q&1)*8 + (j&7)
// -> per (s,h): patch p's 32 B of B (k = 32h..32h+31) is two contiguous 16 B chunks 4096 B
//    apart; 32 consecutive patches = 512 B contiguous -> perfectly coalesced dwordx4 loads.
__global__ void k_bmat8(const float* __restrict__ x, uchar_t* __restrict__ bmk) {
    int p = blockIdx.x; int pr = p >> 4, pc = p & 15;
    for (int e = threadIdx.x; e < CH * KS * KS; e += 256) {
        int c = e / (KS * KS), rem = e % (KS * KS), i = rem / KS, j = rem % KS;
        int o = (j >> 3) * 72 + c * 24 + i;          // k-plane 0..215
        int s = o >> 3, w = o & 7;
        int hh = w >> 2, q = w & 3;
        bmk[(((size_t)(s * 2 + hh) * 2 + (q >> 1)) * 256 + p) * 16 + (q & 1) * 8 + (j & 7)] =
            f2e4m3(x[(c * XH + pr * KS + i) * XW + pc * KS + j]);
    }
}

// 4 column-shifted fp8 copies: y4[S][c][r][t] = fp8(ydec[c][r][t+S]), S in 0..3, 0-pad OOB.
__global__ void k_y4(const float* __restrict__ yd, uchar_t* __restrict__ y4) {
    int idx = blockIdx.x * 256 + threadIdx.x;
    if (idx >= 4 * 3 * HH * (WW / 4)) return;
    int q = idx % (WW / 4); int rem = idx / (WW / 4);
    int r = rem % HH; rem /= HH;
    int c = rem % 3; int S = rem / 3;
    const float* src = yd + (c * HH + r) * WW;
    union { uchar_t u[4]; unsigned v; } o;
    #pragma unroll
    for (int qq = 0; qq < 4; qq++) {
        int t = q * 4 + qq + S;
        o.u[qq] = f2e4m3(t < WW ? src[t] : 0.f);
    }
    ((unsigned*)(y4 + ((size_t)(S * 3 + c) * HH + r) * WW))[q] = o.v;
}

// -------------------- main MFMA correlation kernel (MX-fp8 K=64, direct-operand reads) ------
// R9 post-mortem: occupancy is NOT the lever (R7 3-wave and R9 4-wave both ~40% of MX peak);
// VALUBusy has been the top counter in every round (50-53%) and the 8 v_movs/MFMA that pack
// ad[] rows into af8 sit on the LDS->MFMA dependency path. This version reads A DIRECTLY
// into the MFMA operand registers: af8 quarter (2 consecutive VGPRs) = one ds_read2_b32.
// Rows shared by the two mt-tiles are read twice (8 ds_read2/step vs 5) — R9 showed +43%
// LDS insts costs ~7%, while this deletes ALL packing movs (~70% of K-loop VALU).
//  * regs: acc 32 + af8 2x8x2buf=32 + bf 16 + misc ~20 = ~100 <= 128 @ (512,4). No spills.
//  * B direct to v8i halves, 2-slice prefetch (R7/R9 scheme). A: 4-copy shift band. LDS 19 KB.

#define KBODY(AFc0, AFc1, BFc, AFn0, AFn1, DOB)                               \
  do {                                                                        \
    {                                                                         \
      const uchar_t* Ap = Abase0 + U;                                         \
      _Pragma("unroll")                                                       \
      for (int q = 0; q < 4; q++) {                                           \
        AFn0[2 * q]     = *(const int*)(Ap + q * 56);                         \
        AFn0[2 * q + 1] = *(const int*)(Ap + q * 56 + 4);                     \
        AFn1[2 * q]     = *(const int*)(Ap + (q + 1) * 56);                   \
        AFn1[2 * q + 1] = *(const int*)(Ap + (q + 1) * 56 + 4);               \
      }                                                                       \
      if (++j3 < 3) U += 448;                                                 \
      else { j3 = 0; if (++c3 < 3) U += 672; else { c3 = 0; U -= 4024; } }    \
    }                                                                         \
    acc[0] = __builtin_amdgcn_mfma_scale_f32_32x32x64_f8f6f4(                 \
        AFc0, BFc, acc[0], 0, 0, 0, 0x7F7F7F7F, 0, 0x7F7F7F7F);               \
    acc[1] = __builtin_amdgcn_mfma_scale_f32_32x32x64_f8f6f4(                 \
        AFc1, BFc, acc[1], 0, 0, 0, 0x7F7F7F7F, 0, 0x7F7F7F7F);               \
    if (DOB) {                                                                \
      *(v4i*)&BFc       = *(const v4i*)(gBbase + gBoff);                      \
      *((v4i*)&BFc + 1) = *(const v4i*)(gBbase + gBoff + 4096);               \
      gBoff += 16384;                                                         \
    }                                                                         \
  } while (0)

__global__ __launch_bounds__(512, 4) void k_corr(
    const uchar_t* __restrict__ y4, const uchar_t* __restrict__ bmk,
    const unsigned* __restrict__ sv, const float* __restrict__ mx,
    ushort_t* __restrict__ ps16)
{
    // ---- XCD-band mapping (heuristic blk%8 -> XCD; wrong mapping only costs speed) ----
    const int xcd = blockIdx.x & 7;
    const int idx = blockIdx.x >> 3;
    const int bstart = (NBY * xcd) >> 3;
    const int bcnt = ((NBY * (xcd + 1)) >> 3) - bstart;
    const int local_by = idx / 48;
    if (local_by >= bcnt) return;                    // idle filler block (exits before barriers)
    const int rem = idx - local_by * 48;
    const int z = rem / 24;                          // patch half
    const int bx = rem - z * 24;
    const int by = bstart + local_by;

    __shared__ __align__(16) uchar_t Aband[19072];   // 4 copies x 84 rows x 56 B (stride 4768)

    const int tid = threadIdx.x;
    const int wave = tid >> 6, lane = tid & 63;
    const int r0 = by * BROWS, w0 = bx * BCOLS;
    const int zbase = z * 128;
    const int l31 = lane & 31, h = lane >> 5;
    const int wn = wave & 3;                         // patch group (32 patches)
    const int wr = wave >> 2;                        // row pair (rows wr*2, wr*2+1)

    // ---- B base: lane covers patch p = zbase + wn*32 + l31, k-half h ----
    const uchar_t* gBbase = bmk + h * 8192 + (size_t)(zbase + wn * 32 + l31) * 16;

    // B slices 0,1 -> named sets (issued early; overlap the A staging below)
    v8i bfA, bfB;
    {
        *(v4i*)&bfA       = *(const v4i*)(gBbase);
        *((v4i*)&bfA + 1) = *(const v4i*)(gBbase + 4096);
        *(v4i*)&bfB       = *(const v4i*)(gBbase + 16384);
        *((v4i*)&bfB + 1) = *(const v4i*)(gBbase + 16384 + 4096);
    }

    // ---- prologue: load A band (rows r0..r0+27, cols w0..w0+55) from the 4 shifted planes ----
    for (int e = tid; e < 4704; e += 512) {          // 4 copies x 84 rows x 14 dwords
        int dw = e % 14;
        int row84 = (e / 14) % 84;
        int S = e / 1176;
        int c = row84 / 28, r = row84 - c * 28;
        int gr = r0 + r; gr = gr < HH ? gr : HH - 1; // clamp feeds only masked-invalid positions
        unsigned v = *(const unsigned*)(y4 + ((size_t)(S * 3 + c) * HH + gr) * WW + w0 + dw * 4);
        *(unsigned*)(Aband + S * 4768 + row84 * 56 + dw * 4) = v;
    }

    // A frag lane base: addr = sh*4768 + (c*28 + ibase + 4h + q + wr*2 + mt)*56 + (l31+8jo-sh)
    //                 = [sh*4767 + l31 + h*224 + wr*112] + U(s) + (mt+q)*56,  sh = l31&3
    const uchar_t* Abase0 = Aband + (l31 & 3) * 4767 + l31 + h * 224 + wr * 112;

    v16f acc[2];
    #pragma unroll
    for (int a = 0; a < 2; a++)
        #pragma unroll
        for (int r = 0; r < 16; r++) acc[a][r] = 0.f;

    __syncthreads();                                 // band visible to all waves (one-time)

    v8i afA0, afA1, afB0, afB1;
    #pragma unroll
    for (int q = 0; q < 4; q++) {                    // A slice 0 (U(0)=0) -> afA sets
        afA0[2 * q]     = *(const int*)(Abase0 + q * 56);
        afA0[2 * q + 1] = *(const int*)(Abase0 + q * 56 + 4);
        afA1[2 * q]     = *(const int*)(Abase0 + (q + 1) * 56);
        afA1[2 * q + 1] = *(const int*)(Abase0 + (q + 1) * 56 + 4);
    }
    int U = 448, j3 = 1, c3 = 0;                     // cursor already advanced to slice 1
    int gBoff = 2 * 16384;                           // next B slice to load

    #pragma unroll 1
    for (int p = 0; p < 12; p++) {                   // S = 0..23
        KBODY(afA0, afA1, bfA, afB0, afB1, 1);
        KBODY(afB0, afB1, bfB, afA0, afA1, 1);
    }
    KBODY(afA0, afA1, bfA, afB0, afB1, 1);           // S = 24 (loads B26 -> bfA)
    KBODY(afB0, afB1, bfB, afA0, afA1, 0);           // S = 25 (reads A26 -> afA)
    {   // tail S = 26: compute-only on the A sets
        acc[0] = __builtin_amdgcn_mfma_scale_f32_32x32x64_f8f6f4(
            afA0, bfA, acc[0], 0, 0, 0, 0x7F7F7F7F, 0, 0x7F7F7F7F);
        acc[1] = __builtin_amdgcn_mfma_scale_f32_32x32x64_f8f6f4(
            afA1, bfA, acc[1], 0, 0, 0, 0x7F7F7F7F, 0, 0x7F7F7F7F);
    }

    // epilogue: approx score + per-patch max over this wave's 64 positions
    float mxp = mx[zbase + wn * 32 + l31];
    float best = -1e30f;
    #pragma unroll
    for (int mt = 0; mt < 2; mt++) {
        int rg = r0 + wr * 2 + mt;
        #pragma unroll
        for (int r = 0; r < 16; r++) {
            int row32 = (r & 3) + 8 * (r >> 2) + 4 * h;   // 32x32 C/D row (m74/m101)
            int wg = w0 + row32;
            bool valid = (rg < HC) && (wg < WC);
            int pos = rg * WC + wg;
            unsigned pv = valid ? sv[pos] : 0u;
            float S1 = bf2f((ushort_t)(pv & 0xFFFF));
            float iv = bf2f((ushort_t)(pv >> 16));
            float sc = valid ? (acc[mt][r] - mxp * S1) * iv : -1e30f;
            best = fmaxf(best, sc);
        }
    }
    best = fmaxf(best, __shfl_xor(best, 32));        // reduce over h
    __syncthreads();                                 // all waves done with Aband; alias as red
    float* red = (float*)Aband;
    if (h == 0) red[wr * 128 + wn * 32 + l31] = best;
    __syncthreads();
    if (tid < 128)
        ps16[(by * NBX + bx) * NP + zbase + tid] = f2bf(fmaxf(red[tid], red[128 + tid]));
}

// -------------------- per-patch top-8 blocks --------------------

__global__ void k_select(const ushort_t* __restrict__ ps16, int* __restrict__ cand) {
    int p = blockIdx.x, tid = threadIdx.x;
    __shared__ float ls[NBLK];
    __shared__ float rs[256];
    __shared__ int   ri[256];
    for (int e = tid; e < NBLK; e += 256) ls[e] = bf2f(ps16[e * NP + p]);
    __syncthreads();
    for (int round = 0; round < NCAND; round++) {
        float bs = -1e38f; int bi = 0;
        for (int e = tid; e < NBLK; e += 256) if (ls[e] > bs) { bs = ls[e]; bi = e; }
        rs[tid] = bs; ri[tid] = bi; __syncthreads();
        for (int st = 128; st > 0; st >>= 1) {
            if (tid < st && rs[tid + st] > rs[tid]) { rs[tid] = rs[tid + st]; ri[tid] = ri[tid + st]; }
            __syncthreads();
        }
        int win = ri[0];
        if (tid == 0) cand[p * NCAND + round] = win;
        if (tid == (win & 255)) ls[win] = -1e38f;
        __syncthreads();
    }
}

// -------------------- exact fp32 rescore (recomputes window sums) + gather --------------------

__global__ void k_rescore(const int* __restrict__ cand, const float* __restrict__ xdec,
                          const float* __restrict__ ydec, const float* __restrict__ mx,
                          const float* __restrict__ yfull, float* __restrict__ out) {
    int p = blockIdx.x, tid = threadIdx.x;
    int pr = p >> 4, pc = p & 15;
    float mxp = mx[p];
    float best = -1e30f; int bpos = 0x7FFFFFFF;
    #pragma unroll 1
    for (int cdp = 0; cdp < 4; cdp++) {
        int cd = cdp * 2 + (tid >> 7);
        int blk = cand[p * NCAND + cd];
        int r0 = (blk / NBX) * BROWS, w0 = (blk % NBX) * BCOLS;
        int pi = tid & 127;
        int rg = r0 + (pi >> 5), wg = w0 + (pi & 31);
        if (rg < HC && wg < WC) {
            float sxy = 0.f, sy = 0.f, sy2 = 0.f;
            for (int c = 0; c < CH; c++) {
                #pragma unroll 1
                for (int i = 0; i < KS; i++) {
                    const float* yr = ydec + (c * HH + rg + i) * WW + wg;
                    const float* xr = xdec + (c * XH + pr * KS + i) * XW + pc * KS;
                    #pragma unroll
                    for (int j = 0; j < KS; j++) {
                        float yv = yr[j];
                        sxy = fmaf(yv, xr[j], sxy);
                        sy += yv;
                        sy2 = fmaf(yv, yv, sy2);
                    }
                }
            }
            float d2 = sy2 - sy * sy * (1.0f / 576.0f);
            int pos = rg * WC + wg;
            float sc = (sxy - mxp * sy) * rsqrtf(fmaxf(d2, 1e-20f));
            if (sc > best || (sc == best && pos < bpos)) { best = sc; bpos = pos; }
        }
    }
    __shared__ float rs[256];
    __shared__ int   ri[256];
    rs[tid] = best; ri[tid] = bpos; __syncthreads();
    for (int st = 128; st > 0; st >>= 1) {
        if (tid < st) {
            if (rs[tid + st] > rs[tid] || (rs[tid + st] == rs[tid] && ri[tid + st] < ri[tid])) {
                rs[tid] = rs[tid + st]; ri[tid] = ri[tid + st];
            }
        }
        __syncthreads();
    }
    int bestpos = ri[0];
    int row = bestpos / WC, col = bestpos % WC;
    for (int e = tid; e < CH * KS * KS; e += 256) {
        int c = e / (KS * KS), rem = e % (KS * KS), i = rem / KS, j = rem % KS;
        out[p * CH * KS * KS + e] = yfull[(c * HH + row + i) * WW + col + j];
    }
}

// -------------------- launch --------------------
// ws footprint: writes end < 12.1 MB (y4 ends at 12,047,488 B; + tiny transient OOB reads)
// — safely under the >=13.7 MB proven previously.

extern "C" void kernel_launch(void* const* d_in, const int* in_sizes, int n_in,
                              void* d_out, int out_size, void* d_ws, size_t ws_size,
                              hipStream_t stream) {
    const float* xdec = (const float*)d_in[0];   // (1,3,384,384)
    const float* ydec = (const float*)d_in[1];   // (1,3,768,768)
    const float* y    = (const float*)d_in[2];   // (1,3,768,768)
    float* out = (float*)d_out;                  // (256,3,24,24)

    float* ws = (float*)d_ws;
    unsigned* sv    = (unsigned*)(ws + 0);         // 555025 u32 packed (ivm<<16)|s1m
    float*    mx    = ws + 555040;                 // 256
    uchar_t*  Bmk   = (uchar_t*)(ws + 555296);     // 442368 B, k-major+lane-contiguous (16B-aligned)
    int*      cand  = (int*)(ws + 665888);         // 2048
    ushort_t* ps16  = (ushort_t*)(ws + 667936);    // 1,148,928 u16 [blk][pat]
    uchar_t*  y4    = (uchar_t*)(ws + 1242400);    // 7,077,888 B (16B-aligned)
    // box-sum temps alias ps16+y4 region (dead before k_y4/k_corr):
    float* ksum  = ws + 667936;                    // 589824
    float* ksum2 = ws + 1257760;                   // 589824
    float* h1    = ws + 1847584;                   // 572160
    float* h2    = ws + 2419744;                   // 572160 (end 2,991,904 < 3,011,872)

    k_colsum<<<(HH * WW + 255) / 256, 256, 0, stream>>>(ydec, ksum, ksum2);
    k_hsum<<<(HH * WC + 255) / 256, 256, 0, stream>>>(ksum, ksum2, h1, h2);
    k_vsum<<<(HC * WC + 255) / 256, 256, 0, stream>>>(h1, h2, sv);
    k_meanx<<<NP, 256, 0, stream>>>(xdec, mx);
    k_bmat8<<<NP, 256, 0, stream>>>(xdec, Bmk);
    k_y4<<<(4 * 3 * HH * (WW / 4) + 255) / 256, 256, 0, stream>>>(ydec, y4);

    k_corr<<<NGRID, 512, 0, stream>>>(y4, Bmk, sv, mx, ps16);
    k_select<<<NP, 256, 0, stream>>>(ps16, cand);
    k_rescore<<<NP, 256, 0, stream>>>(cand, xdec, ydec, mx, y, out);
}

// Round 11
// 421.427 us; speedup vs baseline: 1.2262x; 1.2262x over previous
//
#include <hip/hip_runtime.h>

typedef float v16f __attribute__((ext_vector_type(16)));
typedef int v8i __attribute__((ext_vector_type(8)));
typedef int v4i __attribute__((ext_vector_type(4)));
typedef int v2i __attribute__((ext_vector_type(2)));
typedef unsigned short ushort_t;
typedef unsigned char uchar_t;
typedef long long ll_t;

#define HH 768
#define WW 768
#define CH 3
#define KS 24
#define HC 745
#define WC 745
#define NP 256
#define XH 384
#define XW 384

#define NBX 24            // ceil(745/32)
#define NBY 187           // ceil(745/4)
#define NBLK (NBX*NBY)    // 4488
#define BROWS 4
#define BCOLS 32
#define NSTEP 27          // K=1728 in 64-wide slices (8 octets each)
#define NCAND 8
#define NGRID (8*1152)    // XCD-banded launch (some idle)

__device__ __forceinline__ ushort_t f2bf(float f) {
    union { __bf16 h; ushort_t u; } cv; cv.h = (__bf16)f; return cv.u;
}
__device__ __forceinline__ float bf2f(ushort_t u) {
    union { unsigned u; float f; } cv; cv.u = ((unsigned)u) << 16; return cv.f;
}
// fp32 -> OCP e4m3fn (RNE for normals; grid-round for subnormals). Screen-only precision.
__device__ __forceinline__ uchar_t f2e4m3(float f) {
    unsigned u = __float_as_uint(f);
    unsigned s = (u >> 24) & 0x80;
    float a = fabsf(f);
    if (a < 0.0078125f) {
        int q = (int)(a * 512.0f + 0.5f);
        return (uchar_t)(s | (unsigned)q);
    }
    int e = (int)((u >> 23) & 0xFF);
    unsigned m = (u >> 20) & 7;
    unsigned rest = u & 0xFFFFF;
    if (rest > 0x80000 || (rest == 0x80000 && (m & 1))) { m++; if (m == 8) { m = 0; e++; } }
    int e8 = e - 120;
    if (e8 <= 0) { int q = (int)(a * 512.0f + 0.5f); if (q > 7) q = 7; return (uchar_t)(s | q); }
    if (e8 > 15) return (uchar_t)(s | 0x7E);
    return (uchar_t)(s | ((unsigned)e8 << 3) | m);
}

// -------------------- prep kernels --------------------

// FUSED colsum+hsum: one block per row r. Identical add order as the old two-kernel
// pipeline (ksum[t]=a+b+c, then j=0..23 ascending) -> bitwise-same h1/h2.
__global__ void k_rowsum(const float* __restrict__ y, float* __restrict__ h1,
                         float* __restrict__ h2) {
    int r = blockIdx.x;
    __shared__ float ks[WW], ks2[WW];
    for (int t = threadIdx.x; t < WW; t += 256) {
        float a = y[(0 * HH + r) * WW + t];
        float b = y[(1 * HH + r) * WW + t];
        float c = y[(2 * HH + r) * WW + t];
        ks[t]  = a + b + c;
        ks2[t] = a * a + b * b + c * c;
    }
    __syncthreads();
    for (int w = threadIdx.x; w < WC; w += 256) {
        float s = 0.f, s2 = 0.f;
        #pragma unroll
        for (int j = 0; j < KS; j++) { s += ks[w + j]; s2 += ks2[w + j]; }
        h1[r * WC + w] = s; h2[r * WC + w] = s2;
    }
}

// packed bf16 map: sv[pos] = (ivm<<16) | s1m — ONE epilogue load instead of two.
// Screen-only precision; k_rescore recomputes exactly.
__global__ void k_vsum(const float* __restrict__ h1, const float* __restrict__ h2,
                       unsigned* __restrict__ sv) {
    int idx = blockIdx.x * 256 + threadIdx.x;
    if (idx >= HC * WC) return;
    int r = idx / WC, w = idx % WC;
    float s = 0.f, s2 = 0.f;
    #pragma unroll
    for (int i = 0; i < KS; i++) { s += h1[(r + i) * WC + w]; s2 += h2[(r + i) * WC + w]; }
    float d2 = s2 - s * s * (1.0f / 576.0f);
    sv[idx] = ((unsigned)f2bf(rsqrtf(fmaxf(d2, 1e-20f))) << 16) | (unsigned)f2bf(s);
}

// fp8 patch matrix, K-REORDERED and lane-contiguous (R3/R4/R6/R7-verified layout), with
// the patch-mean reduction FUSED in (same e-stride-256 order + tree as old k_meanx ->
// bitwise-same mx; xdec read once instead of twice).
//   k-plane o' = (j/8)*72 + c*24 + i (0..215), slice s = o'>>3, w = o'&7, h = w>>2, q = w&3.
//   addr = (((s*2+h)*2 + (q>>1))*256 + p)*16 + (q&1)*8 + (j&7)
__global__ void k_bmat8(const float* __restrict__ x, uchar_t* __restrict__ bmk,
                        float* __restrict__ mx) {
    int p = blockIdx.x; int pr = p >> 4, pc = p & 15;
    float sum = 0.f;
    for (int e = threadIdx.x; e < CH * KS * KS; e += 256) {
        int c = e / (KS * KS), rem = e % (KS * KS), i = rem / KS, j = rem % KS;
        float v = x[(c * XH + pr * KS + i) * XW + pc * KS + j];
        sum += v;
        int o = (j >> 3) * 72 + c * 24 + i;          // k-plane 0..215
        int s = o >> 3, w = o & 7;
        int hh = w >> 2, q = w & 3;
        bmk[(((size_t)(s * 2 + hh) * 2 + (q >> 1)) * 256 + p) * 16 + (q & 1) * 8 + (j & 7)] =
            f2e4m3(v);
    }
    __shared__ float red[256];
    red[threadIdx.x] = sum; __syncthreads();
    for (int st = 128; st > 0; st >>= 1) {
        if (threadIdx.x < st) red[threadIdx.x] += red[threadIdx.x + st];
        __syncthreads();
    }
    if (threadIdx.x == 0) mx[p] = red[0] * (1.0f / 1728.0f);
}

// 4 column-shifted fp8 copies: y4[S][c][r][t] = fp8(ydec[c][r][t+S]), S in 0..3, 0-pad OOB.
__global__ void k_y4(const float* __restrict__ yd, uchar_t* __restrict__ y4) {
    int idx = blockIdx.x * 256 + threadIdx.x;
    if (idx >= 4 * 3 * HH * (WW / 4)) return;
    int q = idx % (WW / 4); int rem = idx / (WW / 4);
    int r = rem % HH; rem /= HH;
    int c = rem % 3; int S = rem / 3;
    const float* src = yd + (c * HH + r) * WW;
    union { uchar_t u[4]; unsigned v; } o;
    #pragma unroll
    for (int qq = 0; qq < 4; qq++) {
        int t = q * 4 + qq + S;
        o.u[qq] = f2e4m3(t < WW ? src[t] : 0.f);
    }
    ((unsigned*)(y4 + ((size_t)(S * 3 + c) * HH + r) * WW))[q] = o.v;
}

// -------------------- main MFMA correlation kernel (EXACT R7 — measured best 262 us) -------
// B loaded DIRECTLY to registers from L2-resident Bmk (2x dwordx4/lane/step); B(s+2)
// prefetch into named reg sets; A: 4-copy shift band, conflict-free b32-pair reads.
// No inline asm — compiler owns waitcnt/scheduling. LDS 19 KB. VGPR 84, no spills.

#define KBODY(ADc, BFc, ADn, DOB)                                             \
  do {                                                                        \
    {                                                                         \
      const uchar_t* Ap = Abase0 + U;                                         \
      _Pragma("unroll")                                                       \
      for (int r = 0; r < 7; r++) {                                           \
        ADn[r].x = *(const int*)(Ap + r * 56);                                \
        ADn[r].y = *(const int*)(Ap + r * 56 + 4);                            \
      }                                                                       \
      if (++j3 < 3) U += 448;                                                 \
      else { j3 = 0; if (++c3 < 3) U += 672; else { c3 = 0; U -= 4024; } }    \
    }                                                                         \
    _Pragma("unroll")                                                         \
    for (int mt = 0; mt < 4; mt++) {                                          \
      v8i af8;                                                                \
      _Pragma("unroll")                                                       \
      for (int q = 0; q < 4; q++) {                                           \
        af8[2 * q] = ADc[mt + q].x; af8[2 * q + 1] = ADc[mt + q].y;           \
      }                                                                       \
      acc[mt] = __builtin_amdgcn_mfma_scale_f32_32x32x64_f8f6f4(              \
          af8, BFc, acc[mt], 0, 0, 0, 0x7F7F7F7F, 0, 0x7F7F7F7F);             \
    }                                                                         \
    if (DOB) {                                                                \
      v4i b0 = *(const v4i*)(gBbase + gBoff);                                 \
      v4i b1 = *(const v4i*)(gBbase + gBoff + 4096);                          \
      BFc = __builtin_shufflevector(b0, b1, 0, 1, 2, 3, 4, 5, 6, 7);          \
      gBoff += 16384;                                                         \
    }                                                                         \
  } while (0)

__global__ __launch_bounds__(256, 3) void k_corr(
    const uchar_t* __restrict__ y4, const uchar_t* __restrict__ bmk,
    const unsigned* __restrict__ sv, const float* __restrict__ mx,
    ushort_t* __restrict__ ps16)
{
    // ---- XCD-band mapping (heuristic blk%8 -> XCD; wrong mapping only costs speed) ----
    const int xcd = blockIdx.x & 7;
    const int idx = blockIdx.x >> 3;
    const int bstart = (NBY * xcd) >> 3;
    const int bcnt = ((NBY * (xcd + 1)) >> 3) - bstart;
    const int local_by = idx / 48;
    if (local_by >= bcnt) return;                    // idle filler block
    const int rem = idx - local_by * 48;
    const int z = rem / 24;                          // patch half
    const int bx = rem - z * 24;
    const int by = bstart + local_by;

    __shared__ __align__(16) uchar_t Aband[19072];   // 4 copies x 84 rows x 56 B (stride 4768)

    const int tid = threadIdx.x;
    const int wave = tid >> 6, lane = tid & 63;
    const int r0 = by * BROWS, w0 = bx * BCOLS;
    const int zbase = z * 128;
    const int l31 = lane & 31, h = lane >> 5;
    const int wn = wave;                             // patch group (wave-exclusive)

    // ---- B base: lane covers patch p = zbase + wn*32 + l31, k-half h ----
    const uchar_t* gBbase = bmk + h * 8192 + (size_t)(zbase + wn * 32 + l31) * 16;

    // B slices 0,1 -> named sets (issued early; overlap the A staging below)
    v8i bfA, bfB;
    {
        v4i b0 = *(const v4i*)(gBbase);
        v4i b1 = *(const v4i*)(gBbase + 4096);
        bfA = __builtin_shufflevector(b0, b1, 0, 1, 2, 3, 4, 5, 6, 7);
        v4i b2 = *(const v4i*)(gBbase + 16384);
        v4i b3 = *(const v4i*)(gBbase + 16384 + 4096);
        bfB = __builtin_shufflevector(b2, b3, 0, 1, 2, 3, 4, 5, 6, 7);
    }

    // ---- prologue: load A band (rows r0..r0+27, cols w0..w0+55) from the 4 shifted planes ----
    for (int e = tid; e < 4704; e += 256) {          // 4 copies x 84 rows x 14 dwords
        int dw = e % 14;
        int row84 = (e / 14) % 84;
        int S = e / 1176;
        int c = row84 / 28, r = row84 - c * 28;
        int gr = r0 + r; gr = gr < HH ? gr : HH - 1; // clamp feeds only masked-invalid positions
        unsigned v = *(const unsigned*)(y4 + ((size_t)(S * 3 + c) * HH + gr) * WW + w0 + dw * 4);
        *(unsigned*)(Aband + S * 4768 + row84 * 56 + dw * 4) = v;
    }

    // A frag lane base: addr = sh*4768 + (c*28 + ibase + 4h + q + mt)*56 + (l31 + 8jo - sh)
    //                 = [sh*4767 + l31 + h*224] + U(s) + (mt+q)*56,  sh = l31&3
    const uchar_t* Abase0 = Aband + (l31 & 3) * 4767 + l31 + h * 224;

    v16f acc[4];
    #pragma unroll
    for (int a = 0; a < 4; a++)
        #pragma unroll
        for (int r = 0; r < 16; r++) acc[a][r] = 0.f;

    __syncthreads();                                 // band visible to all waves (one-time)

    v2i adA[7], adB[7];
    #pragma unroll
    for (int r = 0; r < 7; r++) {                    // A slice 0 (U(0)=0)
        adA[r].x = *(const int*)(Abase0 + r * 56);
        adA[r].y = *(const int*)(Abase0 + r * 56 + 4);
    }
    int U = 448, j3 = 1, c3 = 0;                     // cursor already advanced to slice 1
    int gBoff = 2 * 16384;                           // next B slice to load

    #pragma unroll 1
    for (int p = 0; p < 12; p++) {                   // S = 0..23
        KBODY(adA, bfA, adB, 1);
        KBODY(adB, bfB, adA, 1);
    }
    KBODY(adA, bfA, adB, 1);                         // S = 24 (loads B26 -> bfA)
    KBODY(adB, bfB, adA, 0);                         // S = 25 (reads A26 -> adA)
    {   // tail S = 26: compute-only on the A sets
        #pragma unroll
        for (int mt = 0; mt < 4; mt++) {
            v8i af8;
            #pragma unroll
            for (int q = 0; q < 4; q++) {
                af8[2 * q] = adA[mt + q].x; af8[2 * q + 1] = adA[mt + q].y;
            }
            acc[mt] = __builtin_amdgcn_mfma_scale_f32_32x32x64_f8f6f4(
                af8, bfA, acc[mt], 0, 0, 0, 0x7F7F7F7F, 0, 0x7F7F7F7F);
        }
    }

    // epilogue: approx score + per-patch max over this block's 128 positions
    float mxp = mx[zbase + wn * 32 + l31];
    float best = -1e30f;
    #pragma unroll
    for (int mt = 0; mt < 4; mt++) {
        int rg = r0 + mt;
        #pragma unroll
        for (int r = 0; r < 16; r++) {
            int row32 = (r & 3) + 8 * (r >> 2) + 4 * h;   // 32x32 C/D row (m74/m101)
            int wg = w0 + row32;
            bool valid = (rg < HC) && (wg < WC);
            int pos = rg * WC + wg;
            unsigned pv = valid ? sv[pos] : 0u;
            float S1 = bf2f((ushort_t)(pv & 0xFFFF));
            float iv = bf2f((ushort_t)(pv >> 16));
            float sc = valid ? (acc[mt][r] - mxp * S1) * iv : -1e30f;
            best = fmaxf(best, sc);
        }
    }
    best = fmaxf(best, __shfl_xor(best, 32));        // reduce over h
    if (h == 0)
        ps16[(by * NBX + bx) * NP + zbase + wn * 32 + l31] = f2bf(best);
}

// -------------------- per-patch top-8 blocks --------------------

__global__ void k_select(const ushort_t* __restrict__ ps16, int* __restrict__ cand) {
    int p = blockIdx.x, tid = threadIdx.x;
    __shared__ float ls[NBLK];
    __shared__ float rs[256];
    __shared__ int   ri[256];
    for (int e = tid; e < NBLK; e += 256) ls[e] = bf2f(ps16[e * NP + p]);
    __syncthreads();
    for (int round = 0; round < NCAND; round++) {
        float bs = -1e38f; int bi = 0;
        for (int e = tid; e < NBLK; e += 256) if (ls[e] > bs) { bs = ls[e]; bi = e; }
        rs[tid] = bs; ri[tid] = bi; __syncthreads();
        for (int st = 128; st > 0; st >>= 1) {
            if (tid < st && rs[tid + st] > rs[tid]) { rs[tid] = rs[tid + st]; ri[tid] = ri[tid + st]; }
            __syncthreads();
        }
        int win = ri[0];
        if (tid == 0) cand[p * NCAND + round] = win;
        if (tid == (win & 255)) ls[win] = -1e38f;
        __syncthreads();
    }
}

// -------------------- exact fp32 rescore, 8x parallel: one block per (patch, candidate) ----
// 2048 blocks x 128 thr (1 position/thread). Same windows, same lexicographic
// (score, -pos) rule as the old fused kernel -> identical selection.

__global__ void k_rescore2(const int* __restrict__ cand, const float* __restrict__ xdec,
                           const float* __restrict__ ydec, const float* __restrict__ mx,
                           float* __restrict__ rsc, int* __restrict__ rpo) {
    int bid = blockIdx.x;
    int p = bid >> 3, cd = bid & 7;
    int tid = threadIdx.x;
    int pr = p >> 4, pc = p & 15;
    int blk = cand[p * NCAND + cd];
    int r0 = (blk / NBX) * BROWS, w0 = (blk % NBX) * BCOLS;
    int rg = r0 + (tid >> 5), wg = w0 + (tid & 31);
    float best = -1e30f; int bpos = 0x7FFFFFFF;
    if (rg < HC && wg < WC) {
        float mxp = mx[p];
        float sxy = 0.f, sy = 0.f, sy2 = 0.f;
        for (int c = 0; c < CH; c++) {
            #pragma unroll 1
            for (int i = 0; i < KS; i++) {
                const float* yr = ydec + (c * HH + rg + i) * WW + wg;
                const float* xr = xdec + (c * XH + pr * KS + i) * XW + pc * KS;
                #pragma unroll
                for (int j = 0; j < KS; j++) {
                    float yv = yr[j];
                    sxy = fmaf(yv, xr[j], sxy);
                    sy += yv;
                    sy2 = fmaf(yv, yv, sy2);
                }
            }
        }
        float d2 = sy2 - sy * sy * (1.0f / 576.0f);
        best = (sxy - mxp * sy) * rsqrtf(fmaxf(d2, 1e-20f));
        bpos = rg * WC + wg;
    }
    __shared__ float rs[128];
    __shared__ int   ri[128];
    rs[tid] = best; ri[tid] = bpos; __syncthreads();
    for (int st = 64; st > 0; st >>= 1) {
        if (tid < st) {
            if (rs[tid + st] > rs[tid] || (rs[tid + st] == rs[tid] && ri[tid + st] < ri[tid])) {
                rs[tid] = rs[tid + st]; ri[tid] = ri[tid + st];
            }
        }
        __syncthreads();
    }
    if (tid == 0) { rsc[bid] = rs[0]; rpo[bid] = ri[0]; }
}

// -------------------- final per-patch argmax over 8 candidates + gather --------------------

__global__ void k_final(const float* __restrict__ rsc, const int* __restrict__ rpo,
                        const float* __restrict__ yfull, float* __restrict__ out) {
    int p = blockIdx.x, tid = threadIdx.x;
    __shared__ int bp;
    if (tid == 0) {
        float best = -1e30f; int bpos = 0x7FFFFFFF;
        for (int cd = 0; cd < NCAND; cd++) {
            float s = rsc[p * NCAND + cd];
            int   q = rpo[p * NCAND + cd];
            if (s > best || (s == best && q < bpos)) { best = s; bpos = q; }
        }
        bp = bpos;
    }
    __syncthreads();
    int row = bp / WC, col = bp % WC;
    for (int e = tid; e < CH * KS * KS; e += 256) {
        int c = e / (KS * KS), rem = e % (KS * KS), i = rem / KS, j = rem % KS;
        out[p * CH * KS * KS + e] = yfull[(c * HH + row + i) * WW + col + j];
    }
}

// -------------------- launch --------------------
// ws footprint: writes end at 12,063,872 B (rsc/rpo after y4) — under the >=13.7 MB proven.

extern "C" void kernel_launch(void* const* d_in, const int* in_sizes, int n_in,
                              void* d_out, int out_size, void* d_ws, size_t ws_size,
                              hipStream_t stream) {
    const float* xdec = (const float*)d_in[0];   // (1,3,384,384)
    const float* ydec = (const float*)d_in[1];   // (1,3,768,768)
    const float* y    = (const float*)d_in[2];   // (1,3,768,768)
    float* out = (float*)d_out;                  // (256,3,24,24)

    float* ws = (float*)d_ws;
    unsigned* sv    = (unsigned*)(ws + 0);         // 555025 u32 packed (ivm<<16)|s1m
    float*    mx    = ws + 555040;                 // 256
    uchar_t*  Bmk   = (uchar_t*)(ws + 555296);     // 442368 B, k-major+lane-contiguous (16B-aligned)
    int*      cand  = (int*)(ws + 665888);         // 2048
    ushort_t* ps16  = (ushort_t*)(ws + 667936);    // 1,148,928 u16 [blk][pat]
    uchar_t*  y4    = (uchar_t*)(ws + 1242400);    // 7,077,888 B (16B-aligned), ends @ float 3011872
    float*    rsc   = ws + 3011872;                // 2048 rescore scores
    int*      rpo   = (int*)(ws + 3013920);        // 2048 rescore positions (end 12,063,872 B)
    // box-sum temps alias ps16+y4 region (dead before k_y4/k_corr):
    float* h1    = ws + 1847584;                   // 572160
    float* h2    = ws + 2419744;                   // 572160 (end 2,991,904 < 3,011,872)

    k_rowsum<<<HH, 256, 0, stream>>>(ydec, h1, h2);
    k_vsum<<<(HC * WC + 255) / 256, 256, 0, stream>>>(h1, h2, sv);
    k_bmat8<<<NP, 256, 0, stream>>>(xdec, Bmk, mx);
    k_y4<<<(4 * 3 * HH * (WW / 4) + 255) / 256, 256, 0, stream>>>(ydec, y4);

    k_corr<<<NGRID, 256, 0, stream>>>(y4, Bmk, sv, mx, ps16);
    k_select<<<NP, 256, 0, stream>>>(ps16, cand);
    k_rescore2<<<NP * NCAND, 128, 0, stream>>>(cand, xdec, ydec, mx, rsc, rpo);
    k_final<<<NP, 256, 0, stream>>>(rsc, rpo, y, out);
}

// Round 12
// 415.199 us; speedup vs baseline: 1.2446x; 1.0150x over previous
//
#include <hip/hip_runtime.h>

typedef float v16f __attribute__((ext_vector_type(16)));
typedef int v8i __attribute__((ext_vector_type(8)));
typedef int v4i __attribute__((ext_vector_type(4)));
typedef int v2i __attribute__((ext_vector_type(2)));
typedef unsigned short ushort_t;
typedef unsigned char uchar_t;
typedef long long ll_t;

#define HH 768
#define WW 768
#define CH 3
#define KS 24
#define HC 745
#define WC 745
#define NP 256
#define XH 384
#define XW 384

#define NBX 24            // ceil(745/32)
#define NBY 187           // ceil(745/4)
#define NBLK (NBX*NBY)    // 4488
#define BROWS 4
#define BCOLS 32
#define NSTEP 27          // K=1728 in 64-wide slices (8 octets each)
#define NCAND 8
#define NGRID (8*1152)    // XCD-banded launch (some idle)

__device__ __forceinline__ ushort_t f2bf(float f) {
    union { __bf16 h; ushort_t u; } cv; cv.h = (__bf16)f; return cv.u;
}
__device__ __forceinline__ float bf2f(ushort_t u) {
    union { unsigned u; float f; } cv; cv.u = ((unsigned)u) << 16; return cv.f;
}
// fp32 -> OCP e4m3fn (RNE for normals; grid-round for subnormals). Screen-only precision.
__device__ __forceinline__ uchar_t f2e4m3(float f) {
    unsigned u = __float_as_uint(f);
    unsigned s = (u >> 24) & 0x80;
    float a = fabsf(f);
    if (a < 0.0078125f) {
        int q = (int)(a * 512.0f + 0.5f);
        return (uchar_t)(s | (unsigned)q);
    }
    int e = (int)((u >> 23) & 0xFF);
    unsigned m = (u >> 20) & 7;
    unsigned rest = u & 0xFFFFF;
    if (rest > 0x80000 || (rest == 0x80000 && (m & 1))) { m++; if (m == 8) { m = 0; e++; } }
    int e8 = e - 120;
    if (e8 <= 0) { int q = (int)(a * 512.0f + 0.5f); if (q > 7) q = 7; return (uchar_t)(s | q); }
    if (e8 > 15) return (uchar_t)(s | 0x7E);
    return (uchar_t)(s | ((unsigned)e8 << 3) | m);
}

// -------------------- prep kernels --------------------

// FUSED colsum+hsum: one block per row r. Identical add order as the old two-kernel
// pipeline (ksum[t]=a+b+c, then j=0..23 ascending) -> bitwise-same h1/h2.
__global__ void k_rowsum(const float* __restrict__ y, float* __restrict__ h1,
                         float* __restrict__ h2) {
    int r = blockIdx.x;
    __shared__ float ks[WW], ks2[WW];
    for (int t = threadIdx.x; t < WW; t += 256) {
        float a = y[(0 * HH + r) * WW + t];
        float b = y[(1 * HH + r) * WW + t];
        float c = y[(2 * HH + r) * WW + t];
        ks[t]  = a + b + c;
        ks2[t] = a * a + b * b + c * c;
    }
    __syncthreads();
    for (int w = threadIdx.x; w < WC; w += 256) {
        float s = 0.f, s2 = 0.f;
        #pragma unroll
        for (int j = 0; j < KS; j++) { s += ks[w + j]; s2 += ks2[w + j]; }
        h1[r * WC + w] = s; h2[r * WC + w] = s2;
    }
}

// packed bf16 map: sv[pos] = (ivm<<16) | s1m — ONE epilogue load instead of two.
// Screen-only precision; k_rescore recomputes exactly.
__global__ void k_vsum(const float* __restrict__ h1, const float* __restrict__ h2,
                       unsigned* __restrict__ sv) {
    int idx = blockIdx.x * 256 + threadIdx.x;
    if (idx >= HC * WC) return;
    int r = idx / WC, w = idx % WC;
    float s = 0.f, s2 = 0.f;
    #pragma unroll
    for (int i = 0; i < KS; i++) { s += h1[(r + i) * WC + w]; s2 += h2[(r + i) * WC + w]; }
    float d2 = s2 - s * s * (1.0f / 576.0f);
    sv[idx] = ((unsigned)f2bf(rsqrtf(fmaxf(d2, 1e-20f))) << 16) | (unsigned)f2bf(s);
}

// fp8 patch matrix, K-REORDERED and lane-contiguous (R3/R4/R6/R7-verified layout), with
// the patch-mean reduction FUSED in (same e-stride-256 order + tree as old k_meanx ->
// bitwise-same mx; xdec read once instead of twice).
//   k-plane o' = (j/8)*72 + c*24 + i (0..215), slice s = o'>>3, w = o'&7, h = w>>2, q = w&3.
//   addr = (((s*2+h)*2 + (q>>1))*256 + p)*16 + (q&1)*8 + (j&7)
__global__ void k_bmat8(const float* __restrict__ x, uchar_t* __restrict__ bmk,
                        float* __restrict__ mx) {
    int p = blockIdx.x; int pr = p >> 4, pc = p & 15;
    float sum = 0.f;
    for (int e = threadIdx.x; e < CH * KS * KS; e += 256) {
        int c = e / (KS * KS), rem = e % (KS * KS), i = rem / KS, j = rem % KS;
        float v = x[(c * XH + pr * KS + i) * XW + pc * KS + j];
        sum += v;
        int o = (j >> 3) * 72 + c * 24 + i;          // k-plane 0..215
        int s = o >> 3, w = o & 7;
        int hh = w >> 2, q = w & 3;
        bmk[(((size_t)(s * 2 + hh) * 2 + (q >> 1)) * 256 + p) * 16 + (q & 1) * 8 + (j & 7)] =
            f2e4m3(v);
    }
    __shared__ float red[256];
    red[threadIdx.x] = sum; __syncthreads();
    for (int st = 128; st > 0; st >>= 1) {
        if (threadIdx.x < st) red[threadIdx.x] += red[threadIdx.x + st];
        __syncthreads();
    }
    if (threadIdx.x == 0) mx[p] = red[0] * (1.0f / 1728.0f);
}

// 4 column-shifted fp8 copies: y4[S][c][r][t] = fp8(ydec[c][r][t+S]), S in 0..3, 0-pad OOB.
__global__ void k_y4(const float* __restrict__ yd, uchar_t* __restrict__ y4) {
    int idx = blockIdx.x * 256 + threadIdx.x;
    if (idx >= 4 * 3 * HH * (WW / 4)) return;
    int q = idx % (WW / 4); int rem = idx / (WW / 4);
    int r = rem % HH; rem /= HH;
    int c = rem % 3; int S = rem / 3;
    const float* src = yd + (c * HH + r) * WW;
    union { uchar_t u[4]; unsigned v; } o;
    #pragma unroll
    for (int qq = 0; qq < 4; qq++) {
        int t = q * 4 + qq + S;
        o.u[qq] = f2e4m3(t < WW ? src[t] : 0.f);
    }
    ((unsigned*)(y4 + ((size_t)(S * 3 + c) * HH + r) * WW))[q] = o.v;
}

// -------------------- main MFMA correlation kernel (MX-fp8 K=64, de-shuffled B path) -------
// R11 post-mortem: per-wave step wall ~1710 cyc but only ~275 matrix + ~100 issue — ~1300 of
// exposed latency per body. Mechanism identified in R7's KBODY: b0/b1 loads are consumed by
// __builtin_shufflevector ~4 instructions after issue -> compiler must emit a vmcnt wait
// there, exposing ~200-300 cyc of L2 latency EVERY step (prefetch distance defeated).
// Fix (single variable vs R11): load B DIRECTLY into the v8i halves (R9's pattern, proven
// spill-free) on the R7 wave shape. BFc's wait moves to its consuming MFMA one full body
// later (~1700 cyc slack >> L2 latency); 8 shuffle movs/step deleted.

#define KBODY(ADc, BFc, ADn, DOB)                                             \
  do {                                                                        \
    {                                                                         \
      const uchar_t* Ap = Abase0 + U;                                         \
      _Pragma("unroll")                                                       \
      for (int r = 0; r < 7; r++) {                                           \
        ADn[r].x = *(const int*)(Ap + r * 56);                                \
        ADn[r].y = *(const int*)(Ap + r * 56 + 4);                            \
      }                                                                       \
      if (++j3 < 3) U += 448;                                                 \
      else { j3 = 0; if (++c3 < 3) U += 672; else { c3 = 0; U -= 4024; } }    \
    }                                                                         \
    _Pragma("unroll")                                                         \
    for (int mt = 0; mt < 4; mt++) {                                          \
      v8i af8;                                                                \
      _Pragma("unroll")                                                       \
      for (int q = 0; q < 4; q++) {                                           \
        af8[2 * q] = ADc[mt + q].x; af8[2 * q + 1] = ADc[mt + q].y;           \
      }                                                                       \
      acc[mt] = __builtin_amdgcn_mfma_scale_f32_32x32x64_f8f6f4(              \
          af8, BFc, acc[mt], 0, 0, 0, 0x7F7F7F7F, 0, 0x7F7F7F7F);             \
    }                                                                         \
    if (DOB) {                                                                \
      *(v4i*)&BFc       = *(const v4i*)(gBbase + gBoff);                      \
      *((v4i*)&BFc + 1) = *(const v4i*)(gBbase + gBoff + 4096);               \
      gBoff += 16384;                                                         \
    }                                                                         \
  } while (0)

__global__ __launch_bounds__(256, 3) void k_corr(
    const uchar_t* __restrict__ y4, const uchar_t* __restrict__ bmk,
    const unsigned* __restrict__ sv, const float* __restrict__ mx,
    ushort_t* __restrict__ ps16)
{
    // ---- XCD-band mapping (heuristic blk%8 -> XCD; wrong mapping only costs speed) ----
    const int xcd = blockIdx.x & 7;
    const int idx = blockIdx.x >> 3;
    const int bstart = (NBY * xcd) >> 3;
    const int bcnt = ((NBY * (xcd + 1)) >> 3) - bstart;
    const int local_by = idx / 48;
    if (local_by >= bcnt) return;                    // idle filler block
    const int rem = idx - local_by * 48;
    const int z = rem / 24;                          // patch half
    const int bx = rem - z * 24;
    const int by = bstart + local_by;

    __shared__ __align__(16) uchar_t Aband[19072];   // 4 copies x 84 rows x 56 B (stride 4768)

    const int tid = threadIdx.x;
    const int wave = tid >> 6, lane = tid & 63;
    const int r0 = by * BROWS, w0 = bx * BCOLS;
    const int zbase = z * 128;
    const int l31 = lane & 31, h = lane >> 5;
    const int wn = wave;                             // patch group (wave-exclusive)

    // ---- B base: lane covers patch p = zbase + wn*32 + l31, k-half h ----
    const uchar_t* gBbase = bmk + h * 8192 + (size_t)(zbase + wn * 32 + l31) * 16;

    // B slices 0,1 -> named sets, loaded DIRECTLY into v8i halves (no shuffle movs)
    v8i bfA, bfB;
    {
        *(v4i*)&bfA       = *(const v4i*)(gBbase);
        *((v4i*)&bfA + 1) = *(const v4i*)(gBbase + 4096);
        *(v4i*)&bfB       = *(const v4i*)(gBbase + 16384);
        *((v4i*)&bfB + 1) = *(const v4i*)(gBbase + 16384 + 4096);
    }

    // ---- prologue: load A band (rows r0..r0+27, cols w0..w0+55) from the 4 shifted planes ----
    for (int e = tid; e < 4704; e += 256) {          // 4 copies x 84 rows x 14 dwords
        int dw = e % 14;
        int row84 = (e / 14) % 84;
        int S = e / 1176;
        int c = row84 / 28, r = row84 - c * 28;
        int gr = r0 + r; gr = gr < HH ? gr : HH - 1; // clamp feeds only masked-invalid positions
        unsigned v = *(const unsigned*)(y4 + ((size_t)(S * 3 + c) * HH + gr) * WW + w0 + dw * 4);
        *(unsigned*)(Aband + S * 4768 + row84 * 56 + dw * 4) = v;
    }

    // A frag lane base: addr = sh*4768 + (c*28 + ibase + 4h + q + mt)*56 + (l31 + 8jo - sh)
    //                 = [sh*4767 + l31 + h*224] + U(s) + (mt+q)*56,  sh = l31&3
    const uchar_t* Abase0 = Aband + (l31 & 3) * 4767 + l31 + h * 224;

    v16f acc[4];
    #pragma unroll
    for (int a = 0; a < 4; a++)
        #pragma unroll
        for (int r = 0; r < 16; r++) acc[a][r] = 0.f;

    __syncthreads();                                 // band visible to all waves (one-time)

    v2i adA[7], adB[7];
    #pragma unroll
    for (int r = 0; r < 7; r++) {                    // A slice 0 (U(0)=0)
        adA[r].x = *(const int*)(Abase0 + r * 56);
        adA[r].y = *(const int*)(Abase0 + r * 56 + 4);
    }
    int U = 448, j3 = 1, c3 = 0;                     // cursor already advanced to slice 1
    int gBoff = 2 * 16384;                           // next B slice to load

    #pragma unroll 1
    for (int p = 0; p < 12; p++) {                   // S = 0..23
        KBODY(adA, bfA, adB, 1);
        KBODY(adB, bfB, adA, 1);
    }
    KBODY(adA, bfA, adB, 1);                         // S = 24 (loads B26 -> bfA)
    KBODY(adB, bfB, adA, 0);                         // S = 25 (reads A26 -> adA)
    {   // tail S = 26: compute-only on the A sets
        #pragma unroll
        for (int mt = 0; mt < 4; mt++) {
            v8i af8;
            #pragma unroll
            for (int q = 0; q < 4; q++) {
                af8[2 * q] = adA[mt + q].x; af8[2 * q + 1] = adA[mt + q].y;
            }
            acc[mt] = __builtin_amdgcn_mfma_scale_f32_32x32x64_f8f6f4(
                af8, bfA, acc[mt], 0, 0, 0, 0x7F7F7F7F, 0, 0x7F7F7F7F);
        }
    }

    // epilogue: approx score + per-patch max over this block's 128 positions
    float mxp = mx[zbase + wn * 32 + l31];
    float best = -1e30f;
    #pragma unroll
    for (int mt = 0; mt < 4; mt++) {
        int rg = r0 + mt;
        #pragma unroll
        for (int r = 0; r < 16; r++) {
            int row32 = (r & 3) + 8 * (r >> 2) + 4 * h;   // 32x32 C/D row (m74/m101)
            int wg = w0 + row32;
            bool valid = (rg < HC) && (wg < WC);
            int pos = rg * WC + wg;
            unsigned pv = valid ? sv[pos] : 0u;
            float S1 = bf2f((ushort_t)(pv & 0xFFFF));
            float iv = bf2f((ushort_t)(pv >> 16));
            float sc = valid ? (acc[mt][r] - mxp * S1) * iv : -1e30f;
            best = fmaxf(best, sc);
        }
    }
    best = fmaxf(best, __shfl_xor(best, 32));        // reduce over h
    if (h == 0)
        ps16[(by * NBX + bx) * NP + zbase + wn * 32 + l31] = f2bf(best);
}

// -------------------- per-patch top-8 blocks --------------------

__global__ void k_select(const ushort_t* __restrict__ ps16, int* __restrict__ cand) {
    int p = blockIdx.x, tid = threadIdx.x;
    __shared__ float ls[NBLK];
    __shared__ float rs[256];
    __shared__ int   ri[256];
    for (int e = tid; e < NBLK; e += 256) ls[e] = bf2f(ps16[e * NP + p]);
    __syncthreads();
    for (int round = 0; round < NCAND; round++) {
        float bs = -1e38f; int bi = 0;
        for (int e = tid; e < NBLK; e += 256) if (ls[e] > bs) { bs = ls[e]; bi = e; }
        rs[tid] = bs; ri[tid] = bi; __syncthreads();
        for (int st = 128; st > 0; st >>= 1) {
            if (tid < st && rs[tid + st] > rs[tid]) { rs[tid] = rs[tid + st]; ri[tid] = ri[tid + st]; }
            __syncthreads();
        }
        int win = ri[0];
        if (tid == 0) cand[p * NCAND + round] = win;
        if (tid == (win & 255)) ls[win] = -1e38f;
        __syncthreads();
    }
}

// -------------------- exact fp32 rescore, 8x parallel: one block per (patch, candidate) ----
// 2048 blocks x 128 thr (1 position/thread). Same windows, same lexicographic
// (score, -pos) rule as the old fused kernel -> identical selection.

__global__ void k_rescore2(const int* __restrict__ cand, const float* __restrict__ xdec,
                           const float* __restrict__ ydec, const float* __restrict__ mx,
                           float* __restrict__ rsc, int* __restrict__ rpo) {
    int bid = blockIdx.x;
    int p = bid >> 3, cd = bid & 7;
    int tid = threadIdx.x;
    int pr = p >> 4, pc = p & 15;
    int blk = cand[p * NCAND + cd];
    int r0 = (blk / NBX) * BROWS, w0 = (blk % NBX) * BCOLS;
    int rg = r0 + (tid >> 5), wg = w0 + (tid & 31);
    float best = -1e30f; int bpos = 0x7FFFFFFF;
    if (rg < HC && wg < WC) {
        float mxp = mx[p];
        float sxy = 0.f, sy = 0.f, sy2 = 0.f;
        for (int c = 0; c < CH; c++) {
            #pragma unroll 1
            for (int i = 0; i < KS; i++) {
                const float* yr = ydec + (c * HH + rg + i) * WW + wg;
                const float* xr = xdec + (c * XH + pr * KS + i) * XW + pc * KS;
                #pragma unroll
                for (int j = 0; j < KS; j++) {
                    float yv = yr[j];
                    sxy = fmaf(yv, xr[j], sxy);
                    sy += yv;
                    sy2 = fmaf(yv, yv, sy2);
                }
            }
        }
        float d2 = sy2 - sy * sy * (1.0f / 576.0f);
        best = (sxy - mxp * sy) * rsqrtf(fmaxf(d2, 1e-20f));
        bpos = rg * WC + wg;
    }
    __shared__ float rs[128];
    __shared__ int   ri[128];
    rs[tid] = best; ri[tid] = bpos; __syncthreads();
    for (int st = 64; st > 0; st >>= 1) {
        if (tid < st) {
            if (rs[tid + st] > rs[tid] || (rs[tid + st] == rs[tid] && ri[tid + st] < ri[tid])) {
                rs[tid] = rs[tid + st]; ri[tid] = ri[tid + st];
            }
        }
        __syncthreads();
    }
    if (tid == 0) { rsc[bid] = rs[0]; rpo[bid] = ri[0]; }
}

// -------------------- final per-patch argmax over 8 candidates + gather --------------------

__global__ void k_final(const float* __restrict__ rsc, const int* __restrict__ rpo,
                        const float* __restrict__ yfull, float* __restrict__ out) {
    int p = blockIdx.x, tid = threadIdx.x;
    __shared__ int bp;
    if (tid == 0) {
        float best = -1e30f; int bpos = 0x7FFFFFFF;
        for (int cd = 0; cd < NCAND; cd++) {
            float s = rsc[p * NCAND + cd];
            int   q = rpo[p * NCAND + cd];
            if (s > best || (s == best && q < bpos)) { best = s; bpos = q; }
        }
        bp = bpos;
    }
    __syncthreads();
    int row = bp / WC, col = bp % WC;
    for (int e = tid; e < CH * KS * KS; e += 256) {
        int c = e / (KS * KS), rem = e % (KS * KS), i = rem / KS, j = rem % KS;
        out[p * CH * KS * KS + e] = yfull[(c * HH + row + i) * WW + col + j];
    }
}

// -------------------- launch --------------------
// ws footprint: writes end at 12,063,872 B (rsc/rpo after y4) — under the >=13.7 MB proven.

extern "C" void kernel_launch(void* const* d_in, const int* in_sizes, int n_in,
                              void* d_out, int out_size, void* d_ws, size_t ws_size,
                              hipStream_t stream) {
    const float* xdec = (const float*)d_in[0];   // (1,3,384,384)
    const float* ydec = (const float*)d_in[1];   // (1,3,768,768)
    const float* y    = (const float*)d_in[2];   // (1,3,768,768)
    float* out = (float*)d_out;                  // (256,3,24,24)

    float* ws = (float*)d_ws;
    unsigned* sv    = (unsigned*)(ws + 0);         // 555025 u32 packed (ivm<<16)|s1m
    float*    mx    = ws + 555040;                 // 256
    uchar_t*  Bmk   = (uchar_t*)(ws + 555296);     // 442368 B, k-major+lane-contiguous (16B-aligned)
    int*      cand  = (int*)(ws + 665888);         // 2048
    ushort_t* ps16  = (ushort_t*)(ws + 667936);    // 1,148,928 u16 [blk][pat]
    uchar_t*  y4    = (uchar_t*)(ws + 1242400);    // 7,077,888 B (16B-aligned), ends @ float 3011872
    float*    rsc   = ws + 3011872;                // 2048 rescore scores
    int*      rpo   = (int*)(ws + 3013920);        // 2048 rescore positions (end 12,063,872 B)
    // box-sum temps alias ps16+y4 region (dead before k_y4/k_corr):
    float* h1    = ws + 1847584;                   // 572160
    float* h2    = ws + 2419744;                   // 572160 (end 2,991,904 < 3,011,872)

    k_rowsum<<<HH, 256, 0, stream>>>(ydec, h1, h2);
    k_vsum<<<(HC * WC + 255) / 256, 256, 0, stream>>>(h1, h2, sv);
    k_bmat8<<<NP, 256, 0, stream>>>(xdec, Bmk, mx);
    k_y4<<<(4 * 3 * HH * (WW / 4) + 255) / 256, 256, 0, stream>>>(ydec, y4);

    k_corr<<<NGRID, 256, 0, stream>>>(y4, Bmk, sv, mx, ps16);
    k_select<<<NP, 256, 0, stream>>>(ps16, cand);
    k_rescore2<<<NP * NCAND, 128, 0, stream>>>(cand, xdec, ydec, mx, rsc, rpo);
    k_final<<<NP, 256, 0, stream>>>(rsc, rpo, y, out);
}